// Round 2
// baseline (83.396 us; speedup 1.0000x reference)
//
#include <hip/hip_runtime.h>

// GraphSage fused gather + mean-aggregate + dual matvec + ReLU
// adj (16,32,32,16) i32; emb (1000001,128) f32; W,b (128,128) f32
// out (16,32,32,128) f32.  Rows = 16384, 16 rows per block, 1024 blocks.

constexpr int DIM   = 128;
constexpr int KN    = 16;     // neighbors incl. self
constexpr int RPB   = 16;     // rows per block
constexpr int NROWS = 16 * 32 * 32;  // 16384

__global__ __launch_bounds__(256, 4)
void graphsage_fused(const int* __restrict__ adj,
                     const float* __restrict__ emb,
                     const float* __restrict__ W,
                     const float* __restrict__ Bm,
                     float* __restrict__ out)
{
    __shared__ float xs_lds[RPB][DIM];   // x_self
    __shared__ float ag_lds[RPB][DIM];   // mean of neighbors
    __shared__ int   idx_lds[RPB * KN];

    const int t    = threadIdx.x;
    const int row0 = blockIdx.x * RPB;

    // stage the 256 adjacency indices for this block's 16 rows
    idx_lds[t] = adj[row0 * KN + t];
    __syncthreads();

    // ---- Phase A: gather + mean ----
    // thread t: row r = t>>4, dim chunk dbase = (t&15)*8 (8 floats)
    {
        const int r     = t >> 4;
        const int dbase = (t & 15) * 8;
        float4 x0, x1;
        float4 a0 = make_float4(0.f, 0.f, 0.f, 0.f);
        float4 a1 = make_float4(0.f, 0.f, 0.f, 0.f);
        #pragma unroll
        for (int k = 0; k < KN; ++k) {
            const int e = idx_lds[r * KN + k];
            const float4* p =
                reinterpret_cast<const float4*>(emb + (size_t)e * DIM + dbase);
            const float4 v0 = p[0];
            const float4 v1 = p[1];
            if (k == 0) { x0 = v0; x1 = v1; }
            else {
                a0.x += v0.x; a0.y += v0.y; a0.z += v0.z; a0.w += v0.w;
                a1.x += v1.x; a1.y += v1.y; a1.z += v1.z; a1.w += v1.w;
            }
        }
        const float s = 1.0f / 15.0f;
        a0.x *= s; a0.y *= s; a0.z *= s; a0.w *= s;
        a1.x *= s; a1.y *= s; a1.z *= s; a1.w *= s;
        *reinterpret_cast<float4*>(&xs_lds[r][dbase])     = x0;
        *reinterpret_cast<float4*>(&xs_lds[r][dbase + 4]) = x1;
        *reinterpret_cast<float4*>(&ag_lds[r][dbase])     = a0;
        *reinterpret_cast<float4*>(&ag_lds[r][dbase + 4]) = a1;
    }
    __syncthreads();

    // ---- Phase B: out[row][h] = relu(agg·W[:,h] + xs·b[:,h]) ----
    // thread t: row r = t>>4, cols hb..hb+7 with hb = (t&15)*8.
    // LDS reads are 4-unique-address broadcasts; W/b reads are coalesced
    // float4 (512 B per 16-lane group, broadcast across groups).
    {
        const int r  = t >> 4;
        const int hb = (t & 15) * 8;
        float acc[8] = {};
        #pragma unroll 2
        for (int d0 = 0; d0 < DIM; d0 += 4) {
            const float4 ag = *reinterpret_cast<const float4*>(&ag_lds[r][d0]);
            const float4 xs = *reinterpret_cast<const float4*>(&xs_lds[r][d0]);
            #pragma unroll
            for (int dd = 0; dd < 4; ++dd) {
                const float a = (&ag.x)[dd];
                const float x = (&xs.x)[dd];
                const float4 w0 = *reinterpret_cast<const float4*>(W  + (d0 + dd) * DIM + hb);
                const float4 w1 = *reinterpret_cast<const float4*>(W  + (d0 + dd) * DIM + hb + 4);
                const float4 b0 = *reinterpret_cast<const float4*>(Bm + (d0 + dd) * DIM + hb);
                const float4 b1 = *reinterpret_cast<const float4*>(Bm + (d0 + dd) * DIM + hb + 4);
                acc[0] += a * w0.x + x * b0.x;
                acc[1] += a * w0.y + x * b0.y;
                acc[2] += a * w0.z + x * b0.z;
                acc[3] += a * w0.w + x * b0.w;
                acc[4] += a * w1.x + x * b1.x;
                acc[5] += a * w1.y + x * b1.y;
                acc[6] += a * w1.z + x * b1.z;
                acc[7] += a * w1.w + x * b1.w;
            }
        }
        float4 o0, o1;
        o0.x = fmaxf(acc[0], 0.0f); o0.y = fmaxf(acc[1], 0.0f);
        o0.z = fmaxf(acc[2], 0.0f); o0.w = fmaxf(acc[3], 0.0f);
        o1.x = fmaxf(acc[4], 0.0f); o1.y = fmaxf(acc[5], 0.0f);
        o1.z = fmaxf(acc[6], 0.0f); o1.w = fmaxf(acc[7], 0.0f);
        float* o = out + (size_t)(row0 + r) * DIM + hb;
        *reinterpret_cast<float4*>(o)     = o0;
        *reinterpret_cast<float4*>(o + 4) = o1;
    }
}

extern "C" void kernel_launch(void* const* d_in, const int* in_sizes, int n_in,
                              void* d_out, int out_size, void* d_ws, size_t ws_size,
                              hipStream_t stream) {
    const int*   adj = (const int*)  d_in[0];
    const float* emb = (const float*)d_in[1];
    const float* W   = (const float*)d_in[2];
    const float* b   = (const float*)d_in[3];
    float*       out = (float*)d_out;

    dim3 grid(NROWS / RPB);   // 1024 blocks
    dim3 block(256);
    graphsage_fused<<<grid, block, 0, stream>>>(adj, emb, W, b, out);
}

// Round 3
// 34.222 us; speedup vs baseline: 2.4369x; 2.4369x over previous
//
#include <hip/hip_runtime.h>
#include <hip/hip_bf16.h>

// GraphSage fused: gather + mean + [agg|xs]·[W;b] via bf16 MFMA + ReLU
// adj (16,32,32,16) i32; emb (1000001,128) f32; W,b (128,128) f32
// out (16,32,32,128) f32.  Rows = 16384, 16 rows/block, 1024 blocks.
// d_ws holds WbT[128][256] bf16 (64 KB): WbT[n][k] = (k<128 ? W[k][n] : b[k-128][n]).

constexpr int DIM   = 128;
constexpr int KN    = 16;
constexpr int RPB   = 16;
constexpr int NROWS = 16 * 32 * 32;      // 16384
constexpr int LDA   = 264;               // shorts per LDS A-row (256 + 8 pad -> 528 B)

typedef __bf16 bf16x8 __attribute__((ext_vector_type(8)));
typedef float  f32x4  __attribute__((ext_vector_type(4)));

__device__ __forceinline__ unsigned short f2b(float x) {
    __bf16 h = (__bf16)x;                 // RTNE
    return __builtin_bit_cast(unsigned short, h);
}

// ---- prep: build WbT (bf16, n-major) in workspace ----
__global__ void prep_wbt(const float* __restrict__ W, const float* __restrict__ Bm,
                         unsigned short* __restrict__ WbT) {
    const int n = blockIdx.x;            // 0..127
    const int k = threadIdx.x;           // 0..255
    const float v = (k < DIM) ? W[k * DIM + n] : Bm[(k - DIM) * DIM + n];
    WbT[n * 256 + k] = f2b(v);
}

// ---- main fused kernel ----
__global__ __launch_bounds__(256, 4)
void graphsage_mfma(const int* __restrict__ adj,
                    const float* __restrict__ emb,
                    const unsigned short* __restrict__ WbT,
                    float* __restrict__ out)
{
    __shared__ unsigned short ldsA[RPB * LDA];   // 16 x 264 shorts = 8.25 KB
    __shared__ int idx_lds[RPB * KN];

    const int t    = threadIdx.x;
    const int row0 = blockIdx.x * RPB;

    idx_lds[t] = adj[row0 * KN + t];
    __syncthreads();

    // ---- Phase A: gather + mean, convert to bf16, store A-tile ----
    // thread t: row r = t>>4, dim chunk dbase = (t&15)*8 (8 floats)
    {
        const int r     = t >> 4;
        const int c16   = t & 15;        // 16B-chunk index within the k=0..127 half
        const int dbase = c16 * 8;
        float4 x0, x1;
        float4 a0 = make_float4(0.f, 0.f, 0.f, 0.f);
        float4 a1 = make_float4(0.f, 0.f, 0.f, 0.f);
        #pragma unroll
        for (int k = 0; k < KN; ++k) {
            const int e = idx_lds[r * KN + k];
            const float4* p =
                reinterpret_cast<const float4*>(emb + (size_t)e * DIM + dbase);
            const float4 v0 = p[0];
            const float4 v1 = p[1];
            if (k == 0) { x0 = v0; x1 = v1; }
            else {
                a0.x += v0.x; a0.y += v0.y; a0.z += v0.z; a0.w += v0.w;
                a1.x += v1.x; a1.y += v1.y; a1.z += v1.z; a1.w += v1.w;
            }
        }
        const float s = 1.0f / 15.0f;
        union { unsigned short u[8]; uint4 q; } pa, px;
        pa.u[0] = f2b(a0.x * s); pa.u[1] = f2b(a0.y * s);
        pa.u[2] = f2b(a0.z * s); pa.u[3] = f2b(a0.w * s);
        pa.u[4] = f2b(a1.x * s); pa.u[5] = f2b(a1.y * s);
        pa.u[6] = f2b(a1.z * s); pa.u[7] = f2b(a1.w * s);
        px.u[0] = f2b(x0.x); px.u[1] = f2b(x0.y);
        px.u[2] = f2b(x0.z); px.u[3] = f2b(x0.w);
        px.u[4] = f2b(x1.x); px.u[5] = f2b(x1.y);
        px.u[6] = f2b(x1.z); px.u[7] = f2b(x1.w);
        // k-space: [0..127] = agg, [128..255] = x_self
        *reinterpret_cast<uint4*>(&ldsA[r * LDA + c16 * 8])        = pa.q;
        *reinterpret_cast<uint4*>(&ldsA[r * LDA + (16 + c16) * 8]) = px.q;
    }
    __syncthreads();

    // ---- Phase B: MFMA.  wave w -> cols [32w, 32w+32); two 16x16 n-tiles ----
    {
        const int wid  = t >> 6;
        const int lane = t & 63;
        const int col  = lane & 15;
        const int g    = lane >> 4;          // k-quarter within MFMA step
        const int n0   = wid * 32;

        f32x4 acc0 = {0.f, 0.f, 0.f, 0.f};
        f32x4 acc1 = {0.f, 0.f, 0.f, 0.f};
        const int arow = lane & 15;

        #pragma unroll
        for (int s = 0; s < 8; ++s) {
            const int c = s * 4 + g;         // 16B chunk index (k = s*32 + g*8)
            bf16x8 a = __builtin_bit_cast(bf16x8,
                *reinterpret_cast<const uint4*>(&ldsA[arow * LDA + c * 8]));
            bf16x8 b0 = __builtin_bit_cast(bf16x8,
                *reinterpret_cast<const uint4*>(WbT + (n0 + col) * 256 + s * 32 + g * 8));
            bf16x8 b1 = __builtin_bit_cast(bf16x8,
                *reinterpret_cast<const uint4*>(WbT + (n0 + 16 + col) * 256 + s * 32 + g * 8));
            acc0 = __builtin_amdgcn_mfma_f32_16x16x32_bf16(a, b0, acc0, 0, 0, 0);
            acc1 = __builtin_amdgcn_mfma_f32_16x16x32_bf16(a, b1, acc1, 0, 0, 0);
        }

        // D layout: col = lane&15, row = (lane>>4)*4 + reg  [m89-verified]
        #pragma unroll
        for (int reg = 0; reg < 4; ++reg) {
            const int rr = g * 4 + reg;
            float* o = out + (size_t)(row0 + rr) * DIM;
            o[n0 + col]      = fmaxf(acc0[reg], 0.0f);
            o[n0 + 16 + col] = fmaxf(acc1[reg], 0.0f);
        }
    }
}

extern "C" void kernel_launch(void* const* d_in, const int* in_sizes, int n_in,
                              void* d_out, int out_size, void* d_ws, size_t ws_size,
                              hipStream_t stream) {
    const int*   adj = (const int*)  d_in[0];
    const float* emb = (const float*)d_in[1];
    const float* W   = (const float*)d_in[2];
    const float* b   = (const float*)d_in[3];
    float*       out = (float*)d_out;
    unsigned short* WbT = (unsigned short*)d_ws;   // 64 KB

    prep_wbt<<<dim3(DIM), dim3(256), 0, stream>>>(W, b, WbT);
    graphsage_mfma<<<dim3(NROWS / RPB), dim3(256), 0, stream>>>(adj, emb, WbT, out);
}

// Round 4
// 28.348 us; speedup vs baseline: 2.9419x; 1.2072x over previous
//
#include <hip/hip_runtime.h>
#include <hip/hip_bf16.h>

// GraphSage fused single-kernel: gather + mean + [agg|xs]·[W;b] bf16-MFMA + ReLU
// adj (16,32,32,16) i32; emb (1000001,128) f32; W,b (128,128) f32
// out (16,32,32,128) f32.  Rows = 16384, 16 rows/block, 1024 blocks.
// B-operands converted fp32->bf16 in-register per wave (no prep kernel, no ws).

constexpr int DIM   = 128;
constexpr int KN    = 16;
constexpr int RPB   = 16;
constexpr int NROWS = 16 * 32 * 32;      // 16384
constexpr int LDA   = 264;               // shorts per LDS A-row (256 + 8 pad)

typedef __bf16 bf16x8 __attribute__((ext_vector_type(8)));
typedef float  f32x4  __attribute__((ext_vector_type(4)));

__device__ __forceinline__ unsigned short f2b(float x) {
    __bf16 h = (__bf16)x;                 // RTNE
    return __builtin_bit_cast(unsigned short, h);
}

__global__ __launch_bounds__(256, 4)
void graphsage_mfma(const int* __restrict__ adj,
                    const float* __restrict__ emb,
                    const float* __restrict__ W,
                    const float* __restrict__ Bm,
                    float* __restrict__ out)
{
    __shared__ unsigned short ldsA[RPB * LDA];   // 16 x 264 shorts = 8.25 KB
    __shared__ int idx_lds[RPB * KN];

    const int t    = threadIdx.x;
    const int row0 = blockIdx.x * RPB;

    idx_lds[t] = adj[row0 * KN + t];
    __syncthreads();

    // ---- Phase A: gather + mean, convert to bf16, store A-tile ----
    {
        const int r     = t >> 4;
        const int c16   = t & 15;
        const int dbase = c16 * 8;
        float4 x0, x1;
        float4 a0 = make_float4(0.f, 0.f, 0.f, 0.f);
        float4 a1 = make_float4(0.f, 0.f, 0.f, 0.f);
        #pragma unroll
        for (int k = 0; k < KN; ++k) {
            const int e = idx_lds[r * KN + k];
            const float4* p =
                reinterpret_cast<const float4*>(emb + (size_t)e * DIM + dbase);
            const float4 v0 = p[0];
            const float4 v1 = p[1];
            if (k == 0) { x0 = v0; x1 = v1; }
            else {
                a0.x += v0.x; a0.y += v0.y; a0.z += v0.z; a0.w += v0.w;
                a1.x += v1.x; a1.y += v1.y; a1.z += v1.z; a1.w += v1.w;
            }
        }
        const float s = 1.0f / 15.0f;
        union { unsigned short u[8]; uint4 q; } pa, px;
        pa.u[0] = f2b(a0.x * s); pa.u[1] = f2b(a0.y * s);
        pa.u[2] = f2b(a0.z * s); pa.u[3] = f2b(a0.w * s);
        pa.u[4] = f2b(a1.x * s); pa.u[5] = f2b(a1.y * s);
        pa.u[6] = f2b(a1.z * s); pa.u[7] = f2b(a1.w * s);
        px.u[0] = f2b(x0.x); px.u[1] = f2b(x0.y);
        px.u[2] = f2b(x0.z); px.u[3] = f2b(x0.w);
        px.u[4] = f2b(x1.x); px.u[5] = f2b(x1.y);
        px.u[6] = f2b(x1.z); px.u[7] = f2b(x1.w);
        // k-space: [0..127] = agg (·W), [128..255] = x_self (·b)
        *reinterpret_cast<uint4*>(&ldsA[r * LDA + c16 * 8])        = pa.q;
        *reinterpret_cast<uint4*>(&ldsA[r * LDA + (16 + c16) * 8]) = px.q;
    }
    __syncthreads();

    // ---- Phase B: MFMA.  wave w -> cols [32w, 32w+32) ----
    {
        const int wid  = t >> 6;
        const int lane = t & 63;
        const int col  = lane & 15;
        const int g    = lane >> 4;          // k-group within 32-k MFMA step
        const int n0   = wid * 32;

        f32x4 acc0 = {0.f, 0.f, 0.f, 0.f};
        f32x4 acc1 = {0.f, 0.f, 0.f, 0.f};
        const int arow = lane & 15;

        #pragma unroll
        for (int s = 0; s < 8; ++s) {
            const int c = s * 4 + g;         // 16B chunk: k = s*32 + g*8
            bf16x8 a = __builtin_bit_cast(bf16x8,
                *reinterpret_cast<const uint4*>(&ldsA[arow * LDA + c * 8]));
            // B operand from global fp32 (L2-resident), convert in-register.
            // k-space s<4 -> W (agg half), s>=4 -> b (x_self half).
            const float* __restrict__ M = (s < 4) ? W : Bm;
            const int k0 = (s & 3) * 32 + g * 8;
            union { unsigned short u[8]; bf16x8 v; } b0u, b1u;
            #pragma unroll
            for (int j = 0; j < 8; ++j) {
                const float* rowp = M + (size_t)(k0 + j) * DIM + n0;
                b0u.u[j] = f2b(rowp[col]);
                b1u.u[j] = f2b(rowp[16 + col]);
            }
            acc0 = __builtin_amdgcn_mfma_f32_16x16x32_bf16(a, b0u.v, acc0, 0, 0, 0);
            acc1 = __builtin_amdgcn_mfma_f32_16x16x32_bf16(a, b1u.v, acc1, 0, 0, 0);
        }

        // D layout: col = lane&15, row = (lane>>4)*4 + reg
        #pragma unroll
        for (int reg = 0; reg < 4; ++reg) {
            const int rr = g * 4 + reg;
            float* o = out + (size_t)(row0 + rr) * DIM;
            o[n0 + col]      = fmaxf(acc0[reg], 0.0f);
            o[n0 + 16 + col] = fmaxf(acc1[reg], 0.0f);
        }
    }
}

extern "C" void kernel_launch(void* const* d_in, const int* in_sizes, int n_in,
                              void* d_out, int out_size, void* d_ws, size_t ws_size,
                              hipStream_t stream) {
    const int*   adj = (const int*)  d_in[0];
    const float* emb = (const float*)d_in[1];
    const float* W   = (const float*)d_in[2];
    const float* b   = (const float*)d_in[3];
    float*       out = (float*)d_out;

    graphsage_mfma<<<dim3(NROWS / RPB), dim3(256), 0, stream>>>(adj, emb, W, b, out);
}